// Round 13
// baseline (784.809 us; speedup 1.0000x reference)
//
#include <hip/hip_runtime.h>
#include <hip/hip_bf16.h>

#define NREL 14
#define NE     100000
#define NEDGE  (NREL*NE)
#define NN     100000
#define EPF    800000
#define NQ     370000                 // sum of dst-range sizes over relations
#define NB1    ((NQ + 1023) / 1024)   // scan blocks = 362
#define QWAVES 5786                   // sum ceil(nd/64) (also GEMM blocks)
#define TWAVES 1564                   // sum ceil(typesize/64)

__device__ __constant__ int d_dlo[NREL]   = {10000,30000,70000,30000,70000,70000,0,0,0,10000,30000,10000,30000,70000};
__device__ __constant__ int d_qoff[NREL+1]= {0,20000,60000,90000,130000,160000,190000,200000,210000,220000,240000,280000,300000,340000,370000};
__device__ __constant__ int d_qwoff[NREL+1]={0,313,938,1407,2032,2501,2970,3127,3284,3441,3754,4379,4692,5317,5786};
__device__ __constant__ int d_trel[4][4]  = {{6,7,8,-1},{0,9,11,-1},{1,3,10,12},{2,4,5,13}};
__device__ __constant__ int d_ntrel[4]    = {3,3,4,4};
__device__ __constant__ int d_tbase[5]    = {0,10000,30000,70000,100000};
__device__ __constant__ int d_twoff[5]    = {0,157,470,1095,1564};

__device__ __forceinline__ float csig(float v, float lo, float hi) {
    float mid = 0.5f * (lo + hi);
    float s = 1.0f / (1.0f + expf(-0.1f * (v - mid)));
    return (s - 0.5f) * (hi - lo) + mid;
}

// ==================== tiled-GEMM building blocks ===========================
template<int K>
__device__ __forceinline__ void stage_in(
    float* sIn, const float* __restrict__ src, int l0, int n, int tid)
{
    if (K == 4) {
        if (tid < 64) {
            int lcl = min(l0 + tid, n - 1);
            float4 v = *(const float4*)(src + (long)lcl * 4);
            sIn[0 * 64 + tid] = v.x; sIn[1 * 64 + tid] = v.y;
            sIn[2 * 64 + tid] = v.z; sIn[3 * 64 + tid] = v.w;
        }
    } else {
        int row = tid >> 2, q = tid & 3;
        int lcl = min(l0 + row, n - 1);
        const float* p = src + (long)lcl * 64 + q * 16;
        #pragma unroll
        for (int kk = 0; kk < 4; ++kk) {
            float4 v = *(const float4*)(p + kk * 4);
            int k = q * 16 + kk * 4;
            sIn[(k + 0) * 64 + row] = v.x;
            sIn[(k + 1) * 64 + row] = v.y;
            sIn[(k + 2) * 64 + row] = v.z;
            sIn[(k + 3) * 64 + row] = v.w;
        }
    }
}

template<int K>
__device__ __forceinline__ void stage_w(
    float* sW, const float* __restrict__ src, int tid)
{
    for (int i = tid * 4; i < K * 64; i += 1024)
        *(float4*)(sW + i) = *(const float4*)(src + i);
}

template<int K>
__device__ __forceinline__ void mma_t(
    float acc[4][4], const float* sIn, const float* sW, int r0, int c0)
{
    for (int k = 0; k < K; ++k) {
        float4 a = *(const float4*)(sIn + k * 64 + r0);
        float4 b = *(const float4*)(sW + k * 64 + c0);
        acc[0][0] = fmaf(a.x, b.x, acc[0][0]);
        acc[0][1] = fmaf(a.x, b.y, acc[0][1]);
        acc[0][2] = fmaf(a.x, b.z, acc[0][2]);
        acc[0][3] = fmaf(a.x, b.w, acc[0][3]);
        acc[1][0] = fmaf(a.y, b.x, acc[1][0]);
        acc[1][1] = fmaf(a.y, b.y, acc[1][1]);
        acc[1][2] = fmaf(a.y, b.z, acc[1][2]);
        acc[1][3] = fmaf(a.y, b.w, acc[1][3]);
        acc[2][0] = fmaf(a.z, b.x, acc[2][0]);
        acc[2][1] = fmaf(a.z, b.y, acc[2][1]);
        acc[2][2] = fmaf(a.z, b.z, acc[2][2]);
        acc[2][3] = fmaf(a.z, b.w, acc[2][3]);
        acc[3][0] = fmaf(a.w, b.x, acc[3][0]);
        acc[3][1] = fmaf(a.w, b.y, acc[3][1]);
        acc[3][2] = fmaf(a.w, b.z, acc[3][2]);
        acc[3][3] = fmaf(a.w, b.w, acc[3][3]);
    }
}

// ---- combined skip weights: Wc[t] = sum_{r: dst_type==t} Ws[r] -------------
template<int DIN>
__global__ __launch_bounds__(256) void combine_skip(
    const float* __restrict__ Ws, float* __restrict__ Wc)
{
    int tid = blockIdx.x * blockDim.x + threadIdx.x;
    if (tid >= 4 * DIN * 64) return;
    int t = tid / (DIN * 64), o = tid % (DIN * 64);
    float s = 0.f;
    for (int ri = 0; ri < d_ntrel[t]; ++ri) s += Ws[d_trel[t][ri] * DIN * 64 + o];
    Wc[tid] = s;
}

// ---- relation prep ---------------------------------------------------------
template<int DIN>
__global__ __launch_bounds__(256) void mk_m2t(
    const float* __restrict__ Wk, const float* __restrict__ Wq,
    float* __restrict__ M2T)
{
    int tid = blockIdx.x * blockDim.x + threadIdx.x;
    if (tid >= NREL * DIN * DIN) return;
    int r = tid / (DIN * DIN), rem = tid % (DIN * DIN);
    int i = rem / DIN, j = rem % DIN;
    const float* wki = Wk + (long)r * DIN * 64 + i * 64;
    const float* wqj = Wq + (long)r * DIN * 64 + j * 64;
    float s = 0.f;
    for (int c = 0; c < 64; ++c) s = fmaf(wki[c], wqj[c], s);
    M2T[(long)r * DIN * DIN + j * DIN + i] = s;
}

// vec4[r][k][i]: k=0: Wk bq (u init); k=1: Wq we0; k=2: Wq we1; k=3: Wq bk
template<int DIN>
__global__ __launch_bounds__(256) void mk_vecs(
    const float* __restrict__ Wk, const float* __restrict__ Wq,
    const float* __restrict__ bq, const float* __restrict__ bk,
    const float* __restrict__ We, float* __restrict__ vec4)
{
    int tid = blockIdx.x * blockDim.x + threadIdx.x;
    if (tid >= NREL * 4 * DIN) return;
    int r = tid / (4 * DIN), rem = tid % (4 * DIN);
    int k = rem / DIN, i = rem % DIN;
    const float* row; const float* v;
    if (k == 0) { row = Wk + (long)r * DIN * 64 + i * 64; v = bq + r * 64; }
    else {
        row = Wq + (long)r * DIN * 64 + i * 64;
        v = (k == 1) ? We + r * 128 : (k == 2) ? We + r * 128 + 64 : bk + r * 64;
    }
    float s = 0.f;
    for (int c = 0; c < 64; ++c) s = fmaf(row[c], v[c], s);
    vec4[tid] = s;
}

// scl[r] = (bq.we0, bq.we1, bk.bq, 0)
__global__ __launch_bounds__(64) void mk_scl(
    const float* __restrict__ bq, const float* __restrict__ bk,
    const float* __restrict__ We, float* __restrict__ scl)
{
    int r = blockIdx.x * blockDim.x + threadIdx.x;
    if (r >= NREL) return;
    float s0 = 0.f, s1 = 0.f, sb = 0.f;
    for (int c = 0; c < 64; ++c) {
        float b = bq[r * 64 + c];
        s0 = fmaf(b, We[r * 128 + c], s0);
        s1 = fmaf(b, We[r * 128 + 64 + c], s1);
        sb = fmaf(b, bk[r * 64 + c], sb);
    }
    scl[4 * r] = s0; scl[4 * r + 1] = s1; scl[4 * r + 2] = sb; scl[4 * r + 3] = 0.f;
}

// ---- CSR build (static graph) ---------------------------------------------
__global__ __launch_bounds__(256) void csr_count(
    const int* __restrict__ edst, int* __restrict__ cur)
{
    int tid = blockIdx.x * blockDim.x + threadIdx.x;
    if (tid >= NEDGE) return;
    int r = tid / NE;
    atomicAdd(&cur[d_qoff[r] + edst[tid] - d_dlo[r]], 1);
}

__global__ __launch_bounds__(1024) void scan1(
    const int* __restrict__ cur, int* __restrict__ rowst, int* __restrict__ bsum)
{
    __shared__ int s[1024];
    int t = threadIdx.x, g = blockIdx.x * 1024 + t;
    s[t] = g < NQ ? cur[g] : 0;
    __syncthreads();
    for (int o = 1; o < 1024; o <<= 1) {
        int x = t >= o ? s[t - o] : 0;
        __syncthreads();
        s[t] += x;
        __syncthreads();
    }
    if (g < NQ) rowst[g + 1] = s[t];
    if (t == 1023) bsum[blockIdx.x] = s[1023];
}

__global__ __launch_bounds__(512) void scan2(int* __restrict__ bsum)
{
    __shared__ int s[512];
    int t = threadIdx.x;
    s[t] = t < NB1 ? bsum[t] : 0;
    __syncthreads();
    for (int o = 1; o < 512; o <<= 1) {
        int x = t >= o ? s[t - o] : 0;
        __syncthreads();
        s[t] += x;
        __syncthreads();
    }
    if (t < NB1) bsum[t] = (t == 0) ? 0 : s[t - 1];
}

__global__ __launch_bounds__(256) void scan3(
    const int* __restrict__ bsum, int* __restrict__ rowst)
{
    int g = blockIdx.x * blockDim.x + threadIdx.x;
    if (g == 0) rowst[0] = 0;
    if (g < NQ) rowst[g + 1] += bsum[g >> 10];
}

__global__ __launch_bounds__(256) void csr_fill(
    const int* __restrict__ edst, const int* __restrict__ rowst,
    int* __restrict__ cur, int* __restrict__ elist)
{
    int tid = blockIdx.x * blockDim.x + threadIdx.x;
    if (tid >= NEDGE) return;
    int r = tid / NE;
    int idx = d_qoff[r] + edst[tid] - d_dlo[r];
    int pos = rowst[idx] + atomicAdd(&cur[idx], 1);
    elist[pos] = tid;
}

// ---- layer-0 fused: inline u + branchless online softmax gather -----------
__global__ __launch_bounds__(256) void gfuse_t40(
    const float* __restrict__ h, const float* __restrict__ M2T,
    const float* __restrict__ vec4, const float* __restrict__ scl,
    const int* __restrict__ esrc, const float* __restrict__ eattr,
    const int* __restrict__ rowst, const int* __restrict__ elist,
    float* __restrict__ ug, float* __restrict__ gm)
{
    int idx = blockIdx.x * blockDim.x + threadIdx.x;
    if (idx >= NQ) return;
    int e0 = rowst[idx], e1 = rowst[idx + 1];
    if (e0 == e1) {
        ((float4*)ug)[idx] = make_float4(0.f, 0.f, 0.f, 0.f);
        gm[2 * (long)idx] = 0.f; gm[2 * (long)idx + 1] = 0.f;
        return;
    }
    int r = 0;
    while (r < NREL - 1 && idx >= d_qoff[r + 1]) ++r;
    int node = d_dlo[r] + (idx - d_qoff[r]);
    float4 hv = ((const float4*)h)[node];
    const float* m2 = M2T + (long)r * 16;
    const float* vb = vec4 + (long)r * 16;
    float4 u;
    u.x = vb[0] + hv.x*m2[0]  + hv.y*m2[4]  + hv.z*m2[8]  + hv.w*m2[12];
    u.y = vb[1] + hv.x*m2[1]  + hv.y*m2[5]  + hv.z*m2[9]  + hv.w*m2[13];
    u.z = vb[2] + hv.x*m2[2]  + hv.y*m2[6]  + hv.z*m2[10] + hv.w*m2[14];
    u.w = vb[3] + hv.x*m2[3]  + hv.y*m2[7]  + hv.z*m2[11] + hv.w*m2[15];
    float sc0 = scl[4*r]   + hv.x*vb[4]  + hv.y*vb[5]  + hv.z*vb[6]  + hv.w*vb[7];
    float sc1 = scl[4*r+1] + hv.x*vb[8]  + hv.y*vb[9]  + hv.z*vb[10] + hv.w*vb[11];
    float scb = scl[4*r+2] + hv.x*vb[12] + hv.y*vb[13] + hv.z*vb[14] + hv.w*vb[15];
    float m = -3.4e38f, den = 0.f, m0 = 0.f, m1 = 0.f;
    float gx = 0.f, gy = 0.f, gz = 0.f, gw = 0.f;
    for (int e = e0; e < e1; ++e) {
        int eid = elist[e];
        float4 hs = ((const float4*)h)[esrc[eid]];
        float2 ea = *(const float2*)(eattr + 2 * (long)eid);
        float alpha = 0.125f * (hs.x*u.x + hs.y*u.y + hs.z*u.z + hs.w*u.w
                                + scb + ea.x * sc0 + ea.y * sc1);
        float nm = fmaxf(m, alpha);
        float s = expf(m - nm);
        float a = expf(alpha - nm);
        m = nm;
        den = den * s + a;
        gx = gx * s + a * hs.x; gy = gy * s + a * hs.y;
        gz = gz * s + a * hs.z; gw = gw * s + a * hs.w;
        m0 = m0 * s + a * ea.x; m1 = m1 * s + a * ea.y;
    }
    float inv = 1.f / (den + 1e-16f);
    ((float4*)ug)[idx] = make_float4(gx*inv, gy*inv, gz*inv, gw*inv);
    gm[2 * (long)idx] = m0 * inv; gm[2 * (long)idx + 1] = m1 * inv;
}

// ---- layer-1 fused: in-LDS u GEMM + scal + quarter-wave edge loop ---------
__global__ __launch_bounds__(256) void gfuse_g(
    const float* __restrict__ h, const float* __restrict__ M2T,
    const float* __restrict__ vec4, const float* __restrict__ scl,
    const int* __restrict__ esrc, const float* __restrict__ eattr,
    const int* __restrict__ rowst, const int* __restrict__ elist,
    float* __restrict__ ug, float* __restrict__ gm)
{
    __shared__ float sA[64 * 64];   // h^T tile (k-major), then U (dst-major)
    __shared__ float sB[64 * 64];   // M2T tile
    __shared__ float sS[64 * 4];    // per-dst scalars
    int blk = blockIdx.x, tid = threadIdx.x;
    int r = 0;
    while (r < NREL - 1 && blk >= d_qwoff[r + 1]) ++r;
    int l0 = (blk - d_qwoff[r]) * 64;
    int nd = d_qoff[r + 1] - d_qoff[r];

    // phase 1: u = M2 h_d + bias (64x64 tile GEMM, u stays on-chip)
    stage_in<64>(sA, h + (long)d_dlo[r] * 64, l0, nd, tid);
    stage_w<64>(sB, M2T + (long)r * 4096, tid);
    __syncthreads();
    int tx = tid & 15, ty = tid >> 4;
    int r0 = ty * 4, c0 = tx * 4;
    float4 bias = *(const float4*)(vec4 + (long)r * 256 + c0);
    float acc[4][4];
    #pragma unroll
    for (int i = 0; i < 4; ++i) {
        acc[i][0] = bias.x; acc[i][1] = bias.y; acc[i][2] = bias.z; acc[i][3] = bias.w;
    }
    mma_t<64>(acc, sA, sB, r0, c0);
    __syncthreads();                   // all mma reads of sA done
    // per-dst scalars from staged h tile (wave 0), before sA overwrite
    if (tid < 64) {
        const float* w1p = vec4 + (long)r * 256 + 64;
        const float* w2p = vec4 + (long)r * 256 + 128;
        const float* w3p = vec4 + (long)r * 256 + 192;
        float s0 = 0.f, s1 = 0.f, s2 = 0.f;
        for (int k = 0; k < 64; ++k) {
            float hv = sA[k * 64 + tid];
            s0 = fmaf(hv, w1p[k], s0);
            s1 = fmaf(hv, w2p[k], s1);
            s2 = fmaf(hv, w3p[k], s2);
        }
        *(float4*)(sS + tid * 4) =
            make_float4(s0 + scl[4*r], s1 + scl[4*r+1], s2 + scl[4*r+2], 0.f);
    }
    __syncthreads();                   // scal reads of sA done
    #pragma unroll
    for (int i = 0; i < 4; ++i)        // write U dst-major into sA
        *(float4*)(sA + (r0 + i) * 64 + c0) =
            make_float4(acc[i][0], acc[i][1], acc[i][2], acc[i][3]);
    __syncthreads();

    // phase 2: quarter-wave (16 lanes/dst) online-softmax gather, 4 dst groups
    int ql = tid & 15;
    for (int grp = 0; grp < 4; ++grp) {
        int dl = grp * 16 + (tid >> 4);
        int lcl = l0 + dl;
        if (lcl >= nd) continue;
        long idx = d_qoff[r] + lcl;
        int e0 = rowst[idx], e1 = rowst[idx + 1];
        long ubase = (long)idx * 64 + ql * 4;
        if (e0 == e1) {
            *(float4*)(ug + ubase) = make_float4(0.f, 0.f, 0.f, 0.f);
            if (ql == 0) { gm[2*idx] = 0.f; gm[2*idx+1] = 0.f; }
            continue;
        }
        float4 u = *(const float4*)(sA + dl * 64 + ql * 4);
        float4 sc = *(const float4*)(sS + dl * 4);
        float m = -3.4e38f, den = 0.f, m0 = 0.f, m1 = 0.f;
        float4 g = make_float4(0.f, 0.f, 0.f, 0.f);
        for (int e = e0; e < e1; ++e) {
            int eid = elist[e];
            int s = esrc[eid];
            float2 ea = *(const float2*)(eattr + 2 * (long)eid);
            float4 hs = *(const float4*)(h + (long)s * 64 + ql * 4);
            float p = hs.x*u.x + hs.y*u.y + hs.z*u.z + hs.w*u.w;
            p += __shfl_xor(p, 1);
            p += __shfl_xor(p, 2);
            p += __shfl_xor(p, 4);
            p += __shfl_xor(p, 8);
            float alpha = 0.125f * (p + sc.z + ea.x * sc.x + ea.y * sc.y);
            float nm = fmaxf(m, alpha);
            float s0 = expf(m - nm);
            float a  = expf(alpha - nm);
            m = nm;
            den = den * s0 + a;
            g.x = g.x * s0 + a * hs.x;
            g.y = g.y * s0 + a * hs.y;
            g.z = g.z * s0 + a * hs.z;
            g.w = g.w * s0 + a * hs.w;
            m0 = m0 * s0 + a * ea.x;
            m1 = m1 * s0 + a * ea.y;
        }
        float inv = 1.f / (den + 1e-16f);
        *(float4*)(ug + ubase) = make_float4(g.x*inv, g.y*inv, g.z*inv, g.w*inv);
        if (ql == 0) { gm[2*idx] = m0 * inv; gm[2*idx+1] = m1 * inv; }
    }
}

// ---- combine (tiled): out = h@Wc + sum_r [ g@Wv + rank-1 terms ] ----------
template<int K, int RELU>
__global__ __launch_bounds__(256) void combine_g(
    const float* __restrict__ h, const float* __restrict__ Wc,
    const float* __restrict__ bs, const float* __restrict__ Wv,
    const float* __restrict__ bv, const float* __restrict__ We,
    const float* __restrict__ ug, const float* __restrict__ gm,
    const int* __restrict__ rowst, float* __restrict__ outp)
{
    __shared__ float sIn[K * 64];
    __shared__ float sW[K * 64];
    __shared__ float sHe[64], sG0[64], sG1[64];
    int blk = blockIdx.x, tid = threadIdx.x;
    int t = 0;
    while (t < 3 && blk >= d_twoff[t + 1]) ++t;
    int l0 = (blk - d_twoff[t]) * 64;
    int nt = d_tbase[t + 1] - d_tbase[t];
    int tx = tid & 15, ty = tid >> 4;
    int r0 = ty * 4, c0 = tx * 4;
    float acc[4][4];
    #pragma unroll
    for (int i = 0; i < 4; ++i) {
        acc[i][0] = 0.f; acc[i][1] = 0.f; acc[i][2] = 0.f; acc[i][3] = 0.f;
    }
    stage_in<K>(sIn, h + (long)d_tbase[t] * K, l0, nt, tid);
    stage_w<K>(sW, Wc + (long)t * K * 64, tid);
    __syncthreads();
    mma_t<K>(acc, sIn, sW, r0, c0);
    int nr = d_ntrel[t];
    for (int ri = 0; ri < nr; ++ri) {
        int rr = d_trel[t][ri];
        __syncthreads();
        stage_in<K>(sIn, ug + (long)d_qoff[rr] * K, l0, nt, tid);
        stage_w<K>(sW, Wv + (long)rr * K * 64, tid);
        if (tid < 64) {
            int lcl = min(l0 + tid, nt - 1);
            long idx = d_qoff[rr] + lcl;
            sHe[tid] = (rowst[idx + 1] > rowst[idx]) ? 1.f : 0.f;
            sG0[tid] = gm[2 * idx];
            sG1[tid] = gm[2 * idx + 1];
        }
        __syncthreads();
        mma_t<K>(acc, sIn, sW, r0, c0);
        float4 bsr = *(const float4*)(bs + rr * 64 + c0);
        float4 bvr = *(const float4*)(bv + rr * 64 + c0);
        float4 w0  = *(const float4*)(We + rr * 128 + c0);
        float4 w1  = *(const float4*)(We + rr * 128 + 64 + c0);
        #pragma unroll
        for (int i = 0; i < 4; ++i) {
            float he = sHe[r0 + i], g0 = sG0[r0 + i], g1 = sG1[r0 + i];
            acc[i][0] += bsr.x + he * bvr.x + g0 * w0.x + g1 * w1.x;
            acc[i][1] += bsr.y + he * bvr.y + g0 * w0.y + g1 * w1.y;
            acc[i][2] += bsr.z + he * bvr.z + g0 * w0.z + g1 * w1.z;
            acc[i][3] += bsr.w + he * bvr.w + g0 * w0.w + g1 * w1.w;
        }
    }
    #pragma unroll
    for (int i = 0; i < 4; ++i) {
        int lr = l0 + r0 + i;
        if (lr < nt) {
            float4 v = make_float4(acc[i][0], acc[i][1], acc[i][2], acc[i][3]);
            if (RELU) {
                v.x = fmaxf(v.x, 0.f); v.y = fmaxf(v.y, 0.f);
                v.z = fmaxf(v.z, 0.f); v.w = fmaxf(v.w, 0.f);
            }
            *(float4*)(outp + (long)(d_tbase[t] + lr) * 64 + c0) = v;
        }
    }
}

// ---- head / power flow / final --------------------------------------------
__global__ __launch_bounds__(256) void head(
    const float* __restrict__ acc, const float* __restrict__ Wlin,
    float* __restrict__ out4)
{
    int wid  = (blockIdx.x * blockDim.x + threadIdx.x) >> 6;
    int lane = threadIdx.x & 63;
    if (wid >= NN) return;
    float hv = fmaxf(acc[(long)wid * 64 + lane], 0.f);
    float4 w = ((const float4*)Wlin)[lane];
    float p0 = hv * w.x, p1 = hv * w.y, p2 = hv * w.z, p3 = hv * w.w;
    #pragma unroll
    for (int m = 32; m > 0; m >>= 1) {
        p0 += __shfl_xor(p0, m);
        p1 += __shfl_xor(p1, m);
        p2 += __shfl_xor(p2, m);
        p3 += __shfl_xor(p3, m);
    }
    if (lane == 0) {
        out4[4 * (long)wid + 0] = p0;
        out4[4 * (long)wid + 1] = p1;
        out4[4 * (long)wid + 2] = p2;
        out4[4 * (long)wid + 3] = p3;
    }
}

__global__ __launch_bounds__(256) void pf_accum(
    const int* __restrict__ pfi, const int* __restrict__ pfj,
    const float* __restrict__ pfa, const float* __restrict__ out4,
    float* __restrict__ Pb, float* __restrict__ Qp)
{
    int e = blockIdx.x * blockDim.x + threadIdx.x;
    if (e >= EPF) return;
    int i = pfi[e], j = pfj[e];
    float r = pfa[2 * (long)e], x = pfa[2 * (long)e + 1];
    float dn = r * r + x * x;
    float G = r / dn, B = -x / dn;
    float thi = out4[4 * (long)i + 1], thj = out4[4 * (long)j + 1];
    float Vi = fabsf(out4[4 * (long)i]), Vj = fabsf(out4[4 * (long)j]);
    float dlt = thj - thi;
    float cd = cosf(dlt), sd = sinf(dlt);
    float vv = Vi * Vj;
    atomicAdd(&Pb[i], vv * (G * cd + B * sd));
    atomicAdd(&Qp[i], vv * (G * sd - B * cd));
}

__global__ __launch_bounds__(256) void final_out(
    const float* __restrict__ out4, const float* __restrict__ cons,
    const float* __restrict__ xin, const float* __restrict__ Pb,
    const float* __restrict__ Qp, float* __restrict__ out)
{
    int n = blockIdx.x * blockDim.x + threadIdx.x;
    if (n >= NN) return;
    const float* c = cons + 7 * (long)n;
    float th = out4[4 * (long)n + 1];
    float V  = fabsf(out4[4 * (long)n + 0]);
    float o0 = csig(V, c[0], c[1]) / xin[4 * (long)n + 0];
    float o2 = csig(Pb[n], c[3], c[4]);
    float o3 = csig(Qp[n], c[5], c[6]);
    out[4 * (long)n + 0] = o0;
    out[4 * (long)n + 1] = th;
    out[4 * (long)n + 2] = o2;
    out[4 * (long)n + 3] = o3;
}

extern "C" void kernel_launch(void* const* d_in, const int* in_sizes, int n_in,
                              void* d_out, int out_size, void* d_ws, size_t ws_size,
                              hipStream_t stream) {
    const float* xin  = (const float*)d_in[0];
    const float* cons = (const float*)d_in[1];
    const int*   esrc = (const int*)d_in[2];
    const int*   edst = (const int*)d_in[3];
    const float* eatt = (const float*)d_in[4];
    const int*   pfi  = (const int*)d_in[5];
    const int*   pfj  = (const int*)d_in[6];
    const float* pfa  = (const float*)d_in[7];

    const float* Wlin;
    int wb;
    if (in_sizes[8] == 256) { Wlin = (const float*)d_in[8];  wb = 9; }
    else                    { Wlin = (const float*)d_in[26]; wb = 8; }
    const float* Wq0 = (const float*)d_in[wb + 0];
    const float* bq0 = (const float*)d_in[wb + 1];
    const float* Wk0 = (const float*)d_in[wb + 2];
    const float* bk0 = (const float*)d_in[wb + 3];
    const float* Wv0 = (const float*)d_in[wb + 4];
    const float* bv0 = (const float*)d_in[wb + 5];
    const float* We0 = (const float*)d_in[wb + 6];
    const float* Ws0 = (const float*)d_in[wb + 7];
    const float* bs0 = (const float*)d_in[wb + 8];
    const float* Wq1 = (const float*)d_in[wb + 9];
    const float* bq1 = (const float*)d_in[wb + 10];
    const float* Wk1 = (const float*)d_in[wb + 11];
    const float* bk1 = (const float*)d_in[wb + 12];
    const float* Wv1 = (const float*)d_in[wb + 13];
    const float* bv1 = (const float*)d_in[wb + 14];
    const float* We1 = (const float*)d_in[wb + 15];
    const float* Ws1 = (const float*)d_in[wb + 16];
    const float* bs1 = (const float*)d_in[wb + 17];

    // ---- workspace layout (~155 MB) ----
    float* w = (float*)d_ws;
    size_t off = 0;
    float* h1     = w + off; off += (size_t)NN * 64;
    float* acc    = w + off; off += (size_t)NN * 64;
    float* ug     = w + off; off += (size_t)NQ * 64;        // g only (u in LDS)
    float* gm     = w + off; off += (size_t)NQ * 2;
    int*   rowst  = (int*)(w + off); off += NQ + 1;
    int*   cur    = (int*)(w + off); off += NQ;
    int*   bsum   = (int*)(w + off); off += 512;
    int*   elist  = (int*)(w + off); off += NEDGE;
    float* M2T    = w + off; off += (size_t)NREL * 64 * 64;
    float* vec4   = w + off; off += (size_t)NREL * 4 * 64;
    float* sclr   = w + off; off += NREL * 4;
    float* Wc0    = w + off; off += 4 * 4 * 64;
    float* Wc1    = w + off; off += 4 * 64 * 64;
    float* Pb     = w + off; off += NN;
    float* Qp     = w + off; off += NN;
    float* out4   = w + off; off += (size_t)NN * 4;
    if (ws_size < off * sizeof(float)) return;

    const int nodeWaveBlks = (NN + 3) / 4;

    hipMemsetAsync(cur, 0, (size_t)NQ * 4, stream);
    hipMemsetAsync(Pb,  0, (size_t)NN * 4, stream);
    hipMemsetAsync(Qp,  0, (size_t)NN * 4, stream);

    combine_skip<4> <<<(4*4*64 + 255)/256, 256, 0, stream>>>(Ws0, Wc0);
    combine_skip<64><<<(4*64*64 + 255)/256, 256, 0, stream>>>(Ws1, Wc1);

    // CSR (static graph, shared by both layers)
    csr_count<<<(NEDGE + 255)/256, 256, 0, stream>>>(edst, cur);
    scan1<<<NB1, 1024, 0, stream>>>(cur, rowst, bsum);
    scan2<<<1, 512, 0, stream>>>(bsum);
    scan3<<<(NQ + 255)/256, 256, 0, stream>>>(bsum, rowst);
    hipMemsetAsync(cur, 0, (size_t)NQ * 4, stream);
    csr_fill<<<(NEDGE + 255)/256, 256, 0, stream>>>(edst, rowst, cur, elist);

    // ================= layer 0 (din=4, h = x) =================
    mk_m2t<4><<<(NREL*16 + 255)/256, 256, 0, stream>>>(Wk0, Wq0, M2T);
    mk_vecs<4><<<(NREL*16 + 255)/256, 256, 0, stream>>>(Wk0, Wq0, bq0, bk0, We0, vec4);
    mk_scl<<<1, 64, 0, stream>>>(bq0, bk0, We0, sclr);
    gfuse_t40<<<(NQ + 255)/256, 256, 0, stream>>>(xin, M2T, vec4, sclr, esrc, eatt, rowst, elist, ug, gm);
    combine_g<4,1><<<TWAVES, 256, 0, stream>>>(xin, Wc0, bs0, Wv0, bv0, We0, ug, gm, rowst, h1);

    // ================= layer 1 (din=64, h = h1) =================
    mk_m2t<64><<<(NREL*64*64 + 255)/256, 256, 0, stream>>>(Wk1, Wq1, M2T);
    mk_vecs<64><<<(NREL*4*64 + 255)/256, 256, 0, stream>>>(Wk1, Wq1, bq1, bk1, We1, vec4);
    mk_scl<<<1, 64, 0, stream>>>(bq1, bk1, We1, sclr);
    gfuse_g<<<QWAVES, 256, 0, stream>>>(h1, M2T, vec4, sclr, esrc, eatt, rowst, elist, ug, gm);
    combine_g<64,0><<<TWAVES, 256, 0, stream>>>(h1, Wc1, bs1, Wv1, bv1, We1, ug, gm, rowst, acc);

    // ================= head + power flow + final =================
    head<<<nodeWaveBlks, 256, 0, stream>>>(acc, Wlin, out4);
    pf_accum<<<(EPF + 255)/256, 256, 0, stream>>>(pfi, pfj, pfa, out4, Pb, Qp);
    final_out<<<(NN + 255)/256, 256, 0, stream>>>(out4, cons, xin, Pb, Qp, (float*)d_out);
}